// Round 3
// baseline (8786.447 us; speedup 1.0000x reference)
//
#include <hip/hip_runtime.h>
#include <stdint.h>

#define SEQ   4096
#define EMB   256
#define HID   512
#define NTAGS 16
#define START_TAG 14
#define STOP_TAG  15
#define MAGICW 0x9E3779B1u

// ---------------------------------------------------------------------------
// Kernel 1: xp[dir][t][1536] = emb[sent[dir? S-1-t : t]] @ Wih_dir^T + bih_dir
// Tiled GEMM: BM=64 (t), BN=128 (rows), BK=64, K=256. 256 threads, 8x4 microtile.
// ---------------------------------------------------------------------------
__global__ __launch_bounds__(256) void k_xp(
    const int* __restrict__ sent, const float* __restrict__ emb,
    const float* __restrict__ WihF, const float* __restrict__ bihF,
    const float* __restrict__ WihB, const float* __restrict__ bihB,
    float* __restrict__ xp)
{
  __shared__ float XsT[64 * 72];    // [kk][t] padded   (18.4 KB)
  __shared__ float WsT[64 * 132];   // [kk][r] padded   (33.8 KB)

  const int tid = threadIdx.x;
  const int dir = blockIdx.z;
  const float* Wih = dir ? WihB : WihF;
  const float* bih = dir ? bihB : bihF;

  const int tl = tid & 63, q = tid >> 6;          // X loader mapping
  const int tg = blockIdx.x * 64 + tl;
  const int srow = dir ? (SEQ - 1 - tg) : tg;
  const float* xrow = emb + (size_t)sent[srow] * EMB;

  const int r = tid >> 1, hh = tid & 1;           // W loader mapping: 2 thr/row
  const float* wrow = Wih + (size_t)(blockIdx.y * 128 + r) * EMB;

  const int cx = tid & 31, ty = tid >> 5;         // compute mapping
  float acc[8][4] = {};

  for (int kc = 0; kc < 4; kc++) {
    const int kb = kc * 64;
    __syncthreads();
    #pragma unroll
    for (int i = 0; i < 4; i++) {
      float4 v = *(const float4*)(xrow + kb + q * 16 + i * 4);
      int kk = q * 16 + i * 4;
      XsT[(kk + 0) * 72 + tl] = v.x; XsT[(kk + 1) * 72 + tl] = v.y;
      XsT[(kk + 2) * 72 + tl] = v.z; XsT[(kk + 3) * 72 + tl] = v.w;
    }
    // each thread covers k in [hh*32, hh*32+32): 8 x float4
    #pragma unroll
    for (int i = 0; i < 8; i++) {
      float4 v = *(const float4*)(wrow + kb + hh * 32 + i * 4);
      int kk = hh * 32 + i * 4;
      WsT[(kk + 0) * 132 + r] = v.x; WsT[(kk + 1) * 132 + r] = v.y;
      WsT[(kk + 2) * 132 + r] = v.z; WsT[(kk + 3) * 132 + r] = v.w;
    }
    __syncthreads();
    #pragma unroll 4
    for (int kk = 0; kk < 64; kk++) {
      const float4 b  = *(const float4*)&WsT[kk * 132 + cx * 4];
      const float4 x0 = *(const float4*)&XsT[kk * 72 + ty * 8];
      const float4 x1 = *(const float4*)&XsT[kk * 72 + ty * 8 + 4];
      const float av[8] = {x0.x, x0.y, x0.z, x0.w, x1.x, x1.y, x1.z, x1.w};
      const float bv[4] = {b.x, b.y, b.z, b.w};
      #pragma unroll
      for (int i = 0; i < 8; i++)
        #pragma unroll
        for (int j = 0; j < 4; j++)
          acc[i][j] = fmaf(av[i], bv[j], acc[i][j]);
    }
  }

  const float4 bv4 = *(const float4*)(bih + blockIdx.y * 128 + cx * 4);
  #pragma unroll
  for (int i = 0; i < 8; i++) {
    int t = blockIdx.x * 64 + ty * 8 + i;
    float4 o;
    o.x = acc[i][0] + bv4.x; o.y = acc[i][1] + bv4.y;
    o.z = acc[i][2] + bv4.z; o.w = acc[i][3] + bv4.w;
    *(float4*)(xp + ((size_t)dir * SEQ + t) * 1536 + blockIdx.y * 128 + cx * 4) = o;
  }
}

// ---------------------------------------------------------------------------
// Kernel 2: persistent GRU recurrence. 64 WGs: dir = bx>>5, slice g = bx&31.
// Each WG owns h-slice [g*16, g*16+16): 48 rows of Whh, weights in VGPRs.
// Cross-WG sync: stamped (MAGIC,value) u64 words, agent-scope atomics.
// Thread map: rg = tid>>4 (16 row-triples), kq = tid&15 (k-chunk of 32).
// ---------------------------------------------------------------------------
__device__ __forceinline__ int pidx(int k) { return (k >> 6) * 68 + (k & 63); }

__global__ __launch_bounds__(256, 1) void k_rec(
    const float* __restrict__ WhhF, const float* __restrict__ bhhF,
    const float* __restrict__ WhhB, const float* __restrict__ bhhB,
    const float* __restrict__ xp,
    unsigned long long* __restrict__ hcomm)
{
  const int wg  = blockIdx.x;
  const int dir = wg >> 5;
  const int g   = wg & 31;
  const int Cbase = g * 16;
  const int tid = threadIdx.x;
  const int rg = tid >> 4, kq = tid & 15;

  const float* Whh = dir ? WhhB : WhhF;
  const float* bhh = dir ? bhhB : bhhF;
  const float* xpd = xp + (size_t)dir * SEQ * 1536;
  unsigned long long* hcd = hcomm + (size_t)dir * SEQ * HID;

  __shared__ float h_shf[8 * 68];   // padded full h (512 + pad)
  __shared__ float dsg[48];         // per-slice gate dots

  // --- load weights into registers: 3 rows x 32 k each ---
  float4 w4[3][8];
  #pragma unroll
  for (int j = 0; j < 3; j++) {
    int rl = rg * 3 + j;
    int gate = rl >> 4, il = rl & 15;
    const float* wr = Whh + (size_t)(gate * HID + Cbase + il) * HID + kq * 32;
    #pragma unroll
    for (int qq = 0; qq < 8; qq++) w4[j][qq] = *(const float4*)(wr + qq * 4);
  }
  float b3x = 0.f, b3y = 0.f, b3z = 0.f;
  if (tid < 16) {
    b3x = bhh[Cbase + tid];
    b3y = bhh[HID + Cbase + tid];
    b3z = bhh[2 * HID + Cbase + tid];
  }

  const int w0 = tid, w1 = tid + 256;
  const bool own0 = (w0 >= Cbase && w0 < Cbase + 16);
  const bool own1 = (w1 >= Cbase && w1 < Cbase + 16);

  // t=0: h_prev = 0
  h_shf[pidx(w0)] = 0.f;
  h_shf[pidx(w1)] = 0.f;
  __syncthreads();

  for (int t = 0; t < SEQ; t++) {
    // prefetch input projections for this step (independent of h)
    float xr = 0.f, xz = 0.f, xn = 0.f;
    if (tid < 16) {
      const float* xt = xpd + (size_t)t * 1536;
      xr = xt[Cbase + tid];
      xz = xt[HID + Cbase + tid];
      xn = xt[2 * HID + Cbase + tid];
    }

    if (t > 0) {
      unsigned long long* src = hcd + (size_t)(t - 1) * HID;
      bool n0 = !own0, n1 = !own1;
      while (n0 | n1) {
        if (n0) {
          unsigned long long v = __hip_atomic_load(src + w0, __ATOMIC_RELAXED, __HIP_MEMORY_SCOPE_AGENT);
          if ((unsigned)(v >> 32) == MAGICW) {
            h_shf[pidx(w0)] = __uint_as_float((unsigned)(v & 0xffffffffull)); n0 = false;
          }
        }
        if (n1) {
          unsigned long long v = __hip_atomic_load(src + w1, __ATOMIC_RELAXED, __HIP_MEMORY_SCOPE_AGENT);
          if ((unsigned)(v >> 32) == MAGICW) {
            h_shf[pidx(w1)] = __uint_as_float((unsigned)(v & 0xffffffffull)); n1 = false;
          }
        }
      }
    }
    __syncthreads();   // bar1: h_{t-1} complete in LDS

    float hprev = 0.f;
    if (tid < 16) hprev = h_shf[pidx(Cbase + tid)];

    // matvec: 3 rows x 32 k from registers, h broadcast from LDS
    float a0 = 0.f, a1 = 0.f, a2 = 0.f;
    {
      const float4* hs4 = (const float4*)h_shf;
      const int b4 = (kq >> 1) * 17 + (kq & 1) * 8;
      #pragma unroll
      for (int qq = 0; qq < 8; qq++) {
        float4 hv = hs4[b4 + qq];
        a0 = fmaf(w4[0][qq].x, hv.x, a0); a0 = fmaf(w4[0][qq].y, hv.y, a0);
        a0 = fmaf(w4[0][qq].z, hv.z, a0); a0 = fmaf(w4[0][qq].w, hv.w, a0);
        a1 = fmaf(w4[1][qq].x, hv.x, a1); a1 = fmaf(w4[1][qq].y, hv.y, a1);
        a1 = fmaf(w4[1][qq].z, hv.z, a1); a1 = fmaf(w4[1][qq].w, hv.w, a1);
        a2 = fmaf(w4[2][qq].x, hv.x, a2); a2 = fmaf(w4[2][qq].y, hv.y, a2);
        a2 = fmaf(w4[2][qq].z, hv.z, a2); a2 = fmaf(w4[2][qq].w, hv.w, a2);
      }
    }
    #pragma unroll
    for (int m = 1; m < 16; m <<= 1) {
      a0 += __shfl_xor(a0, m); a1 += __shfl_xor(a1, m); a2 += __shfl_xor(a2, m);
    }
    if (kq == 0) {
      dsg[rg * 3 + 0] = a0; dsg[rg * 3 + 1] = a1; dsg[rg * 3 + 2] = a2;
    }
    __syncthreads();   // bar2: dots ready

    if (tid < 16) {
      float hr = dsg[tid], hz = dsg[16 + tid], hn = dsg[32 + tid];
      float rr = 1.f / (1.f + expf(-(xr + hr + b3x)));
      float zz = 1.f / (1.f + expf(-(xz + hz + b3y)));
      float nn = tanhf(xn + rr * (hn + b3z));
      float hnew = (1.f - zz) * nn + zz * hprev;
      h_shf[pidx(Cbase + tid)] = hnew;   // own slice for next step
      unsigned long long pv = ((unsigned long long)MAGICW << 32) |
                              (unsigned long long)__float_as_uint(hnew);
      __hip_atomic_store(&hcd[(size_t)t * HID + Cbase + tid], pv,
                         __ATOMIC_RELAXED, __HIP_MEMORY_SCOPE_AGENT);
    }
  }
}

// ---------------------------------------------------------------------------
// Kernel 3: feats[t][tag] = sum_k (hf[t][k] + hb[S-1-t][k]) * Wout[tag][k] + bout
// One block per 16 t's. h-sum staged in LDS (33 KB < 64 KB static limit);
// Wout (32 KB) read from global — L1/L2 resident, cost dominated by hcomm BW.
// ---------------------------------------------------------------------------
__global__ __launch_bounds__(256) void k_feats(
    const unsigned long long* __restrict__ hcomm,
    const float* __restrict__ Wout, const float* __restrict__ bout,
    float* __restrict__ feats)
{
  __shared__ float hs[16 * 516];   // stride 516: tl slots land on distinct banks
  const int tid = threadIdx.x, bt = blockIdx.x;

  {
    const unsigned long long* hf = hcomm;
    const unsigned long long* hb = hcomm + (size_t)SEQ * HID;
    #pragma unroll 8
    for (int i = 0; i < 32; i++) {
      int e = i * 256 + tid;
      int tl = e >> 9, k = e & 511;
      int t = bt * 16 + tl;
      float vf = __uint_as_float((unsigned)(hf[(size_t)t * HID + k] & 0xffffffffull));
      float vb = __uint_as_float((unsigned)(hb[(size_t)(SEQ - 1 - t) * HID + k] & 0xffffffffull));
      hs[tl * 516 + k] = vf + vb;
    }
  }
  __syncthreads();

  const int tag = tid & 15, tl = tid >> 4;
  const float4* h4  = (const float4*)&hs[tl * 516];
  const float4* w4p = (const float4*)(Wout + (size_t)tag * HID);
  float acc = 0.f;
  #pragma unroll 8
  for (int qq = 0; qq < 128; qq++) {
    float4 a = h4[qq], b = w4p[qq];
    acc = fmaf(a.x, b.x, acc); acc = fmaf(a.y, b.y, acc);
    acc = fmaf(a.z, b.z, acc); acc = fmaf(a.w, b.w, acc);
  }
  int t = bt * 16 + tl;
  feats[t * NTAGS + tag] = acc + bout[tag];
}

// ---------------------------------------------------------------------------
// Kernel 4: Viterbi scan (1 wave, lane = next*4 + prev-group) + map-composition
// backtrace (nibble-packed 16-entry maps, suffix-scan over 64 lanes).
// ---------------------------------------------------------------------------
__device__ __forceinline__ unsigned long long compose_map(
    unsigned long long A, unsigned long long B)  // (A o B)(x) = A(B(x))
{
  unsigned long long r = 0ull;
  #pragma unroll
  for (int i = 0; i < 16; i++) {
    int bi = (int)((B >> (4 * i)) & 15ull);
    unsigned long long ai = (A >> (4 * bi)) & 15ull;
    r |= ai << (4 * i);
  }
  return r;
}

__device__ __forceinline__ unsigned long long pack16(uint4 w)
{
  auto pk = [](unsigned v) -> unsigned {
    unsigned x = v & 0x0F0F0F0Fu;
    unsigned t = x | (x >> 4);
    return (t & 0xFFu) | ((t >> 8) & 0xFF00u);
  };
  return (unsigned long long)pk(w.x) | ((unsigned long long)pk(w.y) << 16) |
         ((unsigned long long)pk(w.z) << 32) | ((unsigned long long)pk(w.w) << 48);
}

__global__ __launch_bounds__(64, 1) void k_vit(
    const float* __restrict__ feats, const float* __restrict__ trans,
    unsigned char* __restrict__ bps, float* __restrict__ out)
{
  const int lane = threadIdx.x;
  const int nx = lane >> 2, pg = lane & 3;

  const float tr0 = trans[nx * 16 + pg * 4 + 0];
  const float tr1 = trans[nx * 16 + pg * 4 + 1];
  const float tr2 = trans[nx * 16 + pg * 4 + 2];
  const float tr3 = trans[nx * 16 + pg * 4 + 3];

  float f0 = (pg * 4 + 0) == START_TAG ? 0.f : -1000.f;
  float f1 = (pg * 4 + 1) == START_TAG ? 0.f : -1000.f;
  float f2 = (pg * 4 + 2) == START_TAG ? 0.f : -1000.f;
  float f3 = (pg * 4 + 3) == START_TAG ? 0.f : -1000.f;

  float ft = feats[nx];   // feats[0][nx]
  for (int t = 0; t < SEQ; t++) {
    float ftn = feats[(t + 1 < SEQ ? t + 1 : t) * NTAGS + nx];
    float best = f0 + tr0; int bi = pg * 4;
    float c1 = f1 + tr1; if (c1 > best) { best = c1; bi = pg * 4 + 1; }
    float c2 = f2 + tr2; if (c2 > best) { best = c2; bi = pg * 4 + 2; }
    float c3 = f3 + tr3; if (c3 > best) { best = c3; bi = pg * 4 + 3; }
    #pragma unroll
    for (int m = 1; m <= 2; m <<= 1) {
      float ov = __shfl_xor(best, m);
      int   oi = __shfl_xor(bi, m);
      if (ov > best || (ov == best && oi < bi)) { best = ov; bi = oi; }
    }
    float fvnew = best + ft;
    if (pg == 0) bps[t * 16 + nx] = (unsigned char)bi;
    f0 = __shfl(fvnew, (pg * 4 + 0) << 2);
    f1 = __shfl(fvnew, (pg * 4 + 1) << 2);
    f2 = __shfl(fvnew, (pg * 4 + 2) << 2);
    f3 = __shfl(fvnew, (pg * 4 + 3) << 2);
    ft = ftn;
  }

  // terminal = fv + trans[STOP][:]; argmax (first-max wins)
  float g0 = __shfl(f0, nx);
  float g1 = __shfl(f1, nx);
  float g2 = __shfl(f2, nx);
  float g3 = __shfl(f3, nx);
  int b2 = lane & 3;
  float fvl = (b2 == 0) ? g0 : (b2 == 1) ? g1 : (b2 == 2) ? g2 : g3;
  float term = (lane < 16) ? (fvl + trans[STOP_TAG * 16 + lane]) : -3.0e38f;
  int ti = (lane < 16) ? lane : 99;
  #pragma unroll
  for (int m = 1; m <= 32; m <<= 1) {
    float ov = __shfl_xor(term, m);
    int   oi = __shfl_xor(ti, m);
    if (ov > term || (ov == term && oi < ti)) { term = ov; ti = oi; }
  }
  if (lane == 0) out[0] = term;
  const int best = ti;

  __threadfence_block();   // ensure all bps stores visible to cross-lane reads

  // --- backtrace: per-lane chunk composition, then suffix scan ---
  const uint4* bp4 = (const uint4*)bps;
  const unsigned long long IDENT = 0xFEDCBA9876543210ull;
  unsigned long long R = IDENT;
  {
    uint4 w = bp4[lane * 64 + 63];
    for (int s = 63; s >= 0; s--) {
      uint4 wn = (s > 0) ? bp4[lane * 64 + s - 1] : w;
      R = compose_map(pack16(w), R);
      w = wn;
    }
  }
  unsigned long long I = R;
  #pragma unroll
  for (int d = 1; d < 64; d <<= 1) {
    unsigned long long o = __shfl_down(I, d);
    if (lane + d < 64) I = compose_map(I, o);
  }
  unsigned long long E = __shfl_down(I, 1);
  if (lane == 63) E = IDENT;

  int cur = (int)((E >> (4 * best)) & 15ull);
  {
    uint4 w = bp4[lane * 64 + 63];
    for (int s = 63; s >= 0; s--) {
      int t = lane * 64 + s;
      uint4 wn = (s > 0) ? bp4[t - 1] : w;
      out[1 + t] = (float)cur;
      unsigned word = (cur < 4) ? w.x : (cur < 8) ? w.y : (cur < 12) ? w.z : w.w;
      cur = (int)((word >> ((cur & 3) * 8)) & 15u);
      w = wn;
    }
  }
}

// ---------------------------------------------------------------------------
extern "C" void kernel_launch(void* const* d_in, const int* in_sizes, int n_in,
                              void* d_out, int out_size, void* d_ws, size_t ws_size,
                              hipStream_t stream)
{
  const int*   sent  = (const int*)d_in[0];
  const float* emb   = (const float*)d_in[1];
  const float* WihF  = (const float*)d_in[2];
  const float* WhhF  = (const float*)d_in[3];
  const float* bihF  = (const float*)d_in[4];
  const float* bhhF  = (const float*)d_in[5];
  const float* WihB  = (const float*)d_in[6];
  const float* WhhB  = (const float*)d_in[7];
  const float* bihB  = (const float*)d_in[8];
  const float* bhhB  = (const float*)d_in[9];
  const float* Wout  = (const float*)d_in[10];
  const float* bout  = (const float*)d_in[11];
  const float* trans = (const float*)d_in[12];
  float* out = (float*)d_out;

  char* ws = (char*)d_ws;
  const size_t xp_bytes = (size_t)2 * SEQ * 1536 * 4;           // 50.3 MB
  const size_t hc_bytes = (size_t)2 * SEQ * HID * 8;            // 33.6 MB
  const size_t ft_bytes = (size_t)SEQ * NTAGS * 4;              // 256 KB
  float*              xp    = (float*)ws;
  unsigned long long* hcomm = (unsigned long long*)(ws + xp_bytes);
  float*              feats = (float*)(ws + xp_bytes + hc_bytes);
  unsigned char*      bps   = (unsigned char*)(ws + xp_bytes + hc_bytes + ft_bytes);

  // clear stamp words so pollers never see a stale MAGIC (graph-replay safety)
  hipMemsetAsync(hcomm, 0, hc_bytes, stream);

  k_xp  <<<dim3(64, 12, 2), 256, 0, stream>>>(sent, emb, WihF, bihF, WihB, bihB, xp);
  k_rec <<<64, 256, 0, stream>>>(WhhF, bhhF, WhhB, bhhB, xp, hcomm);
  k_feats<<<256, 256, 0, stream>>>(hcomm, Wout, bout, feats);
  k_vit <<<1, 64, 0, stream>>>(feats, trans, bps, out);
}